// Round 1
// baseline (711.440 us; speedup 1.0000x reference)
//
#include <hip/hip_runtime.h>
#include <cfloat>

#define SB 1024   // sequence length S = H*W
#define CC 512    // channels
#define NB 8      // batch
#define NH 8      // heads
#define HD 64     // head dim
#define SCALE 0.125f

// ---------------------------------------------------------------------------
// Y[b,o,s] = sum_c W[o,c] * X[b,c,s] + bias[o]
// 64x64 output tile per block, 256 threads, 4x4 micro-tile per thread, TK=16.
// ---------------------------------------------------------------------------
__global__ __launch_bounds__(256)
void conv1x1_gemm(const float* __restrict__ W, const float* __restrict__ bias,
                  const float* __restrict__ X, float* __restrict__ Y,
                  int O, int K)
{
    const int bs = blockIdx.x;   // s-tile (S/64)
    const int bo = blockIdx.y;   // o-tile (O/64)
    const int b  = blockIdx.z;
    const int tid = threadIdx.x;
    const int tx = tid & 15, ty = tid >> 4;

    const float* Xb = X + (size_t)b * K * SB;
    float* Yb = Y + (size_t)b * O * SB;

    __shared__ float As[16][65];   // [k][o]
    __shared__ float Bs[16][65];   // [k][s]

    float acc[4][4];
    #pragma unroll
    for (int i = 0; i < 4; i++)
        #pragma unroll
        for (int j = 0; j < 4; j++) acc[i][j] = 0.f;

    const int aRow = tid >> 2;          // 0..63 (o within tile)
    const int aK4  = (tid & 3) << 2;    // 0,4,8,12
    const int bK   = tid >> 4;          // 0..15
    const int bS4  = (tid & 15) << 2;   // 0..60

    for (int kc = 0; kc < K; kc += 16) {
        __syncthreads();
        float4 av = *(const float4*)&W[(size_t)(bo * 64 + aRow) * K + kc + aK4];
        As[aK4 + 0][aRow] = av.x; As[aK4 + 1][aRow] = av.y;
        As[aK4 + 2][aRow] = av.z; As[aK4 + 3][aRow] = av.w;
        float4 bv = *(const float4*)&Xb[(size_t)(kc + bK) * SB + bs * 64 + bS4];
        Bs[bK][bS4 + 0] = bv.x; Bs[bK][bS4 + 1] = bv.y;
        Bs[bK][bS4 + 2] = bv.z; Bs[bK][bS4 + 3] = bv.w;
        __syncthreads();
        #pragma unroll
        for (int kk = 0; kk < 16; ++kk) {
            float a[4], bb[4];
            #pragma unroll
            for (int i = 0; i < 4; i++) a[i] = As[kk][ty * 4 + i];
            #pragma unroll
            for (int j = 0; j < 4; j++) bb[j] = Bs[kk][tx * 4 + j];
            #pragma unroll
            for (int i = 0; i < 4; i++)
                #pragma unroll
                for (int j = 0; j < 4; j++)
                    acc[i][j] = fmaf(a[i], bb[j], acc[i][j]);
        }
    }
    #pragma unroll
    for (int i = 0; i < 4; i++) {
        const int o = bo * 64 + ty * 4 + i;
        const float bv = bias[o];
        float4 ov;
        ov.x = acc[i][0] + bv; ov.y = acc[i][1] + bv;
        ov.z = acc[i][2] + bv; ov.w = acc[i][3] + bv;
        *(float4*)&Yb[(size_t)o * SB + bs * 64 + tx * 4] = ov;
    }
}

// ---------------------------------------------------------------------------
// Fused masked attention, one block per (q-block of 64, head, batch).
// qkv layout: (B, 3C, S); q[d][s] at qkv[b*3C*S + (h*64+d)*S + s], etc.
// Iterates ALL 16 key tiles (no causal skip) so fully-masked rows reproduce
// the reference's uniform-softmax behavior exactly via -FLT_MAX arithmetic.
// ---------------------------------------------------------------------------
__global__ __launch_bounds__(256)
void attn_fused(const float* __restrict__ qkv, const int* __restrict__ mask,
                float* __restrict__ ctx)
{
    const int qb = blockIdx.x;   // 0..15
    const int h  = blockIdx.y;
    const int b  = blockIdx.z;
    const int tid = threadIdx.x;
    const int tx = tid & 15, ty = tid >> 4;

    const float* Qb = qkv + ((size_t)(b * 3 * CC) + h * HD) * SB;
    const float* Kb = Qb + (size_t)CC * SB;
    const float* Vb = Kb + (size_t)CC * SB;

    __shared__ float Qs[64][65];   // [d][sq], pre-scaled by SCALE
    __shared__ float Ks[64][65];   // [d][tk]
    __shared__ float Vs[64][65];   // [d][tk]
    __shared__ float Ps[64][65];   // [sq][tk] probs; reused for output transpose
    __shared__ float mskv[64];

    {
        const int s4 = (tid & 15) * 4;
        const int d0 = tid >> 4;
        #pragma unroll
        for (int r = 0; r < 4; r++) {
            int d = d0 + r * 16;
            float4 v = *(const float4*)&Qb[(size_t)d * SB + qb * 64 + s4];
            Qs[d][s4 + 0] = v.x * SCALE; Qs[d][s4 + 1] = v.y * SCALE;
            Qs[d][s4 + 2] = v.z * SCALE; Qs[d][s4 + 3] = v.w * SCALE;
        }
    }

    float m[4], l[4], acc[4][4];
    #pragma unroll
    for (int i = 0; i < 4; i++) {
        m[i] = -FLT_MAX; l[i] = 0.f;
        #pragma unroll
        for (int j = 0; j < 4; j++) acc[i][j] = 0.f;
    }

    const int sq_base = qb * 64 + ty * 4;

    for (int t = 0; t < 16; ++t) {
        __syncthreads();
        {
            const int s4 = (tid & 15) * 4;
            const int d0 = tid >> 4;
            #pragma unroll
            for (int r = 0; r < 4; r++) {
                int d = d0 + r * 16;
                float4 kv = *(const float4*)&Kb[(size_t)d * SB + t * 64 + s4];
                Ks[d][s4 + 0] = kv.x; Ks[d][s4 + 1] = kv.y;
                Ks[d][s4 + 2] = kv.z; Ks[d][s4 + 3] = kv.w;
                float4 vv = *(const float4*)&Vb[(size_t)d * SB + t * 64 + s4];
                Vs[d][s4 + 0] = vv.x; Vs[d][s4 + 1] = vv.y;
                Vs[d][s4 + 2] = vv.z; Vs[d][s4 + 3] = vv.w;
            }
            if (tid < 64)
                mskv[tid] = (mask[(size_t)b * SB + t * 64 + tid] != 0) ? 1.f : 0.f;
        }
        __syncthreads();

        // scores = (Q*SCALE)^T K for this 64x64 block
        float sc[4][4];
        #pragma unroll
        for (int i = 0; i < 4; i++)
            #pragma unroll
            for (int j = 0; j < 4; j++) sc[i][j] = 0.f;
        for (int d = 0; d < 64; ++d) {
            float a[4], bb[4];
            #pragma unroll
            for (int i = 0; i < 4; i++) a[i] = Qs[d][ty * 4 + i];
            #pragma unroll
            for (int j = 0; j < 4; j++) bb[j] = Ks[d][tx * 4 + j];
            #pragma unroll
            for (int i = 0; i < 4; i++)
                #pragma unroll
                for (int j = 0; j < 4; j++)
                    sc[i][j] = fmaf(a[i], bb[j], sc[i][j]);
        }

        // causal + key padding mask
        #pragma unroll
        for (int i = 0; i < 4; i++) {
            const int sq = sq_base + i;
            #pragma unroll
            for (int j = 0; j < 4; j++) {
                const int tg = t * 64 + tx * 4 + j;
                if (tg > sq || mskv[tx * 4 + j] != 0.f) sc[i][j] = -FLT_MAX;
            }
        }

        // online softmax update (row spans 16 tx lanes within the wave)
        #pragma unroll
        for (int i = 0; i < 4; i++) {
            float mx = fmaxf(fmaxf(sc[i][0], sc[i][1]), fmaxf(sc[i][2], sc[i][3]));
            #pragma unroll
            for (int o = 1; o < 16; o <<= 1)
                mx = fmaxf(mx, __shfl_xor(mx, o, 64));
            const float mnew = fmaxf(m[i], mx);
            const float f = __expf(m[i] - mnew);   // 0-0 -> 1 for all-masked rows
            float p[4], rsum = 0.f;
            #pragma unroll
            for (int j = 0; j < 4; j++) {
                p[j] = __expf(sc[i][j] - mnew);
                rsum += p[j];
            }
            #pragma unroll
            for (int o = 1; o < 16; o <<= 1)
                rsum += __shfl_xor(rsum, o, 64);
            l[i] = l[i] * f + rsum;
            m[i] = mnew;
            #pragma unroll
            for (int j = 0; j < 4; j++) Ps[ty * 4 + i][tx * 4 + j] = p[j];
            #pragma unroll
            for (int j = 0; j < 4; j++) acc[i][j] *= f;
        }
        __syncthreads();

        // acc += P * V^T  : acc[i][j] over rows sq=ty*4+i, cols d=tx*4+j
        for (int tk = 0; tk < 64; ++tk) {
            float pp[4], vv[4];
            #pragma unroll
            for (int i = 0; i < 4; i++) pp[i] = Ps[ty * 4 + i][tk];
            #pragma unroll
            for (int j = 0; j < 4; j++) vv[j] = Vs[tx * 4 + j][tk];
            #pragma unroll
            for (int i = 0; i < 4; i++)
                #pragma unroll
                for (int j = 0; j < 4; j++)
                    acc[i][j] = fmaf(pp[i], vv[j], acc[i][j]);
        }
    }

    __syncthreads();
    // transpose to [d][sq] through LDS, then coalesced store
    #pragma unroll
    for (int i = 0; i < 4; i++) {
        const float inv = 1.f / l[i];
        #pragma unroll
        for (int j = 0; j < 4; j++)
            Ps[tx * 4 + j][ty * 4 + i] = acc[i][j] * inv;
    }
    __syncthreads();
    {
        const int s4 = (tid & 15) * 4;
        const int d0 = tid >> 4;
        float* ctxb = ctx + ((size_t)b * CC + h * HD) * SB;
        #pragma unroll
        for (int r = 0; r < 4; r++) {
            int d = d0 + r * 16;
            float4 v;
            v.x = Ps[d][s4 + 0]; v.y = Ps[d][s4 + 1];
            v.z = Ps[d][s4 + 2]; v.w = Ps[d][s4 + 3];
            *(float4*)&ctxb[(size_t)d * SB + qb * 64 + s4] = v;
        }
    }
}

extern "C" void kernel_launch(void* const* d_in, const int* in_sizes, int n_in,
                              void* d_out, int out_size, void* d_ws, size_t ws_size,
                              hipStream_t stream) {
    const float* x      = (const float*)d_in[0];
    const int*   amask  = (const int*)d_in[1];
    const float* qkv_w  = (const float*)d_in[2];
    const float* qkv_b  = (const float*)d_in[3];
    const float* proj_w = (const float*)d_in[4];
    const float* proj_b = (const float*)d_in[5];
    float* out = (float*)d_out;

    float* qkv = (float*)d_ws;                          // (B, 3C, S) = 50.3 MB
    float* ctx = qkv + (size_t)NB * 3 * CC * SB;        // (B, C, S)  = 16.8 MB

    dim3 blk(256);
    conv1x1_gemm<<<dim3(SB / 64, 3 * CC / 64, NB), blk, 0, stream>>>(
        qkv_w, qkv_b, x, qkv, 3 * CC, CC);
    attn_fused<<<dim3(SB / 64, NH, NB), blk, 0, stream>>>(qkv, amask, ctx);
    conv1x1_gemm<<<dim3(SB / 64, CC / 64, NB), blk, 0, stream>>>(
        proj_w, proj_b, ctx, out, CC, CC);
}

// Round 2
// 429.216 us; speedup vs baseline: 1.6575x; 1.6575x over previous
//
#include <hip/hip_runtime.h>
#include <cfloat>

#define SB 1024   // sequence length S = H*W
#define CC 512    // channels
#define NB 8      // batch
#define NH 8      // heads
#define HD 64     // head dim
#define SCALE 0.125f

typedef short short8 __attribute__((ext_vector_type(8)));
typedef float f32x4 __attribute__((ext_vector_type(4)));

__device__ __forceinline__ short f2bs(float f) {
    union { float f; unsigned u; } x; x.f = f;
    unsigned r = x.u + 0x7fffu + ((x.u >> 16) & 1u);   // RNE to bf16
    return (short)(r >> 16);
}

// ---------------------------------------------------------------------------
// Y[b,o,s] = sum_c W[o,c] * X[b,c,s] + bias[o]   (fp32, unchanged from R1)
// ---------------------------------------------------------------------------
__global__ __launch_bounds__(256)
void conv1x1_gemm(const float* __restrict__ W, const float* __restrict__ bias,
                  const float* __restrict__ X, float* __restrict__ Y,
                  int O, int K)
{
    const int bs = blockIdx.x;
    const int bo = blockIdx.y;
    const int b  = blockIdx.z;
    const int tid = threadIdx.x;
    const int tx = tid & 15, ty = tid >> 4;

    const float* Xb = X + (size_t)b * K * SB;
    float* Yb = Y + (size_t)b * O * SB;

    __shared__ float As[16][65];
    __shared__ float Bs[16][65];

    float acc[4][4];
    #pragma unroll
    for (int i = 0; i < 4; i++)
        #pragma unroll
        for (int j = 0; j < 4; j++) acc[i][j] = 0.f;

    const int aRow = tid >> 2;
    const int aK4  = (tid & 3) << 2;
    const int bK   = tid >> 4;
    const int bS4  = (tid & 15) << 2;

    for (int kc = 0; kc < K; kc += 16) {
        __syncthreads();
        float4 av = *(const float4*)&W[(size_t)(bo * 64 + aRow) * K + kc + aK4];
        As[aK4 + 0][aRow] = av.x; As[aK4 + 1][aRow] = av.y;
        As[aK4 + 2][aRow] = av.z; As[aK4 + 3][aRow] = av.w;
        float4 bv = *(const float4*)&Xb[(size_t)(kc + bK) * SB + bs * 64 + bS4];
        Bs[bK][bS4 + 0] = bv.x; Bs[bK][bS4 + 1] = bv.y;
        Bs[bK][bS4 + 2] = bv.z; Bs[bK][bS4 + 3] = bv.w;
        __syncthreads();
        #pragma unroll
        for (int kk = 0; kk < 16; ++kk) {
            float a[4], bb[4];
            #pragma unroll
            for (int i = 0; i < 4; i++) a[i] = As[kk][ty * 4 + i];
            #pragma unroll
            for (int j = 0; j < 4; j++) bb[j] = Bs[kk][tx * 4 + j];
            #pragma unroll
            for (int i = 0; i < 4; i++)
                #pragma unroll
                for (int j = 0; j < 4; j++)
                    acc[i][j] = fmaf(a[i], bb[j], acc[i][j]);
        }
    }
    #pragma unroll
    for (int i = 0; i < 4; i++) {
        const int o = bo * 64 + ty * 4 + i;
        const float bv = bias[o];
        float4 ov;
        ov.x = acc[i][0] + bv; ov.y = acc[i][1] + bv;
        ov.z = acc[i][2] + bv; ov.w = acc[i][3] + bv;
        *(float4*)&Yb[(size_t)o * SB + bs * 64 + tx * 4] = ov;
    }
}

// ---------------------------------------------------------------------------
// MFMA bf16 fused attention. Block = (qb, h, b), 4 waves x 16 queries.
// A/B frag layout (16x16x32): A: lane holds A[l&15][8*(l>>4)+j], j=0..7
//                             B: lane holds B[8*(l>>4)+j][l&15]
// C/D: row=(l>>4)*4+r, col=l&15  (guide-verified)
// Processes ALL 16 key tiles so fully-masked rows reproduce the reference's
// uniform softmax exactly via -FLT_MAX arithmetic.
// ---------------------------------------------------------------------------
__global__ __launch_bounds__(256)
void attn_mfma(const float* __restrict__ qkv, const int* __restrict__ mask,
               float* __restrict__ ctx)
{
    const int qb  = blockIdx.x;       // 0..15
    const int h   = blockIdx.y;
    const int b   = blockIdx.z;
    const int tid = threadIdx.x;
    const int wave = tid >> 6;        // 0..3
    const int lane = tid & 63;
    const int lg = lane >> 4;         // 0..3
    const int ln = lane & 15;

    const float* Qg = qkv + ((size_t)(b * 3 * CC) + h * HD) * SB;
    const float* Kg = Qg + (size_t)CC * SB;
    const float* Vg = Kg + (size_t)CC * SB;

    __shared__ short KV[2][64][72];   // [0]=Ks [t][d], [1]=Vs [d][t]
    __shared__ short Ps[64][72];      // P [s][t] bf16
    __shared__ int   msk[64];

    // ---- load Q A-fragments into registers (once), pre-scaled ----
    short8 qa0, qa1;
    {
        const int scol = qb * 64 + wave * 16 + ln;
        #pragma unroll
        for (int j = 0; j < 8; ++j) {
            qa0[j] = f2bs(Qg[(size_t)(8 * lg + j) * SB + scol] * SCALE);
            qa1[j] = f2bs(Qg[(size_t)(32 + 8 * lg + j) * SB + scol] * SCALE);
        }
    }

    float m_[4], l_[4];
    f32x4 acc[4];
    #pragma unroll
    for (int r = 0; r < 4; ++r) { m_[r] = -FLT_MAX; l_[r] = 0.f; }
    #pragma unroll
    for (int nt = 0; nt < 4; ++nt) acc[nt] = (f32x4){0.f, 0.f, 0.f, 0.f};

    const int sc4 = (tid & 15) * 4;   // staging t-quad
    const int dr  = tid >> 4;         // staging d row base

    for (int t = 0; t < 16; ++t) {
        const int tb = t * 64;
        __syncthreads();              // prev PV done before overwriting K/V
        // ---- stage K (transposed [t][d]) and V ([d][t]) as bf16 ----
        #pragma unroll
        for (int r = 0; r < 4; ++r) {
            const int d = dr + r * 16;
            const float4 kv = *(const float4*)&Kg[(size_t)d * SB + tb + sc4];
            KV[0][sc4 + 0][d] = f2bs(kv.x);
            KV[0][sc4 + 1][d] = f2bs(kv.y);
            KV[0][sc4 + 2][d] = f2bs(kv.z);
            KV[0][sc4 + 3][d] = f2bs(kv.w);
            const float4 vv = *(const float4*)&Vg[(size_t)d * SB + tb + sc4];
            KV[1][d][sc4 + 0] = f2bs(vv.x);
            KV[1][d][sc4 + 1] = f2bs(vv.y);
            KV[1][d][sc4 + 2] = f2bs(vv.z);
            KV[1][d][sc4 + 3] = f2bs(vv.w);
        }
        if (tid < 64) msk[tid] = mask[(size_t)b * SB + tb + tid];
        __syncthreads();

        // ---- QK^T: 4 n-tiles x 2 K-chunks ----
        f32x4 sc[4];
        #pragma unroll
        for (int nt = 0; nt < 4; ++nt) {
            short8 kb0 = *(const short8*)&KV[0][ln + 16 * nt][8 * lg];
            short8 kb1 = *(const short8*)&KV[0][ln + 16 * nt][32 + 8 * lg];
            f32x4 z = (f32x4){0.f, 0.f, 0.f, 0.f};
            z = __builtin_amdgcn_mfma_f32_16x16x32_bf16(qa0, kb0, z, 0, 0, 0);
            z = __builtin_amdgcn_mfma_f32_16x16x32_bf16(qa1, kb1, z, 0, 0, 0);
            sc[nt] = z;
        }

        // ---- mask fixup + online softmax (4 rows per lane) ----
        #pragma unroll
        for (int r = 0; r < 4; ++r) {
            const int sq = qb * 64 + wave * 16 + 4 * lg + r;
            float s4[4];
            float mx = -FLT_MAX;
            #pragma unroll
            for (int nt = 0; nt < 4; ++nt) {
                const int tg = tb + 16 * nt + ln;
                float v = sc[nt][r];
                if (tg > sq || msk[16 * nt + ln] != 0) v = -FLT_MAX;
                s4[nt] = v;
                mx = fmaxf(mx, v);
            }
            #pragma unroll
            for (int o = 1; o < 16; o <<= 1)
                mx = fmaxf(mx, __shfl_xor(mx, o, 64));
            const float mnew = fmaxf(m_[r], mx);
            const float f = __expf(m_[r] - mnew);   // 0-0 -> 1 (all-masked rows)
            float p[4], rs = 0.f;
            #pragma unroll
            for (int nt = 0; nt < 4; ++nt) {
                p[nt] = __expf(s4[nt] - mnew);
                rs += p[nt];
            }
            #pragma unroll
            for (int o = 1; o < 16; o <<= 1)
                rs += __shfl_xor(rs, o, 64);
            l_[r] = l_[r] * f + rs;
            m_[r] = mnew;
            #pragma unroll
            for (int nt = 0; nt < 4; ++nt) acc[nt][r] *= f;
            #pragma unroll
            for (int nt = 0; nt < 4; ++nt)
                Ps[wave * 16 + 4 * lg + r][16 * nt + ln] = f2bs(p[nt]);
        }
        __syncthreads();   // Ps visible (within-wave), keep simple

        // ---- PV: acc[s][d] += P[s][t] * V^T[t][d] ----
        short8 pa0 = *(const short8*)&Ps[wave * 16 + ln][8 * lg];
        short8 pa1 = *(const short8*)&Ps[wave * 16 + ln][32 + 8 * lg];
        #pragma unroll
        for (int nt = 0; nt < 4; ++nt) {
            short8 vb0 = *(const short8*)&KV[1][ln + 16 * nt][8 * lg];
            short8 vb1 = *(const short8*)&KV[1][ln + 16 * nt][32 + 8 * lg];
            acc[nt] = __builtin_amdgcn_mfma_f32_16x16x32_bf16(pa0, vb0, acc[nt], 0, 0, 0);
            acc[nt] = __builtin_amdgcn_mfma_f32_16x16x32_bf16(pa1, vb1, acc[nt], 0, 0, 0);
        }
    }

    // ---- epilogue: normalize, transpose via LDS (alias KV), store ----
    __syncthreads();
    float (*Cs)[68] = (float(*)[68])&KV[0][0][0];   // 64x68 f32 = 17408B <= 18432B
    float rl[4];
    #pragma unroll
    for (int r = 0; r < 4; ++r) rl[r] = 1.f / l_[r];
    #pragma unroll
    for (int nt = 0; nt < 4; ++nt)
        #pragma unroll
        for (int r = 0; r < 4; ++r)
            Cs[wave * 16 + 4 * lg + r][16 * nt + ln] = acc[nt][r] * rl[r];
    __syncthreads();
    {
        float* ctxb = ctx + ((size_t)b * CC + h * HD) * SB;
        const int s4 = (tid & 15) * 4;
        #pragma unroll
        for (int rr = 0; rr < 4; ++rr) {
            const int d = (tid >> 4) + 16 * rr;
            float4 v;
            v.x = Cs[s4 + 0][d]; v.y = Cs[s4 + 1][d];
            v.z = Cs[s4 + 2][d]; v.w = Cs[s4 + 3][d];
            *(float4*)&ctxb[(size_t)d * SB + qb * 64 + s4] = v;
        }
    }
}

extern "C" void kernel_launch(void* const* d_in, const int* in_sizes, int n_in,
                              void* d_out, int out_size, void* d_ws, size_t ws_size,
                              hipStream_t stream) {
    const float* x      = (const float*)d_in[0];
    const int*   amask  = (const int*)d_in[1];
    const float* qkv_w  = (const float*)d_in[2];
    const float* qkv_b  = (const float*)d_in[3];
    const float* proj_w = (const float*)d_in[4];
    const float* proj_b = (const float*)d_in[5];
    float* out = (float*)d_out;

    float* qkv = (float*)d_ws;                          // (B, 3C, S)
    float* ctx = qkv + (size_t)NB * 3 * CC * SB;        // (B, C, S)

    dim3 blk(256);
    conv1x1_gemm<<<dim3(SB / 64, 3 * CC / 64, NB), blk, 0, stream>>>(
        qkv_w, qkv_b, x, qkv, 3 * CC, CC);
    attn_mfma<<<dim3(SB / 64, NH, NB), blk, 0, stream>>>(qkv, amask, ctx);
    conv1x1_gemm<<<dim3(SB / 64, CC / 64, NB), blk, 0, stream>>>(
        proj_w, proj_b, ctx, out, CC, CC);
}

// Round 3
// 120.944 us; speedup vs baseline: 5.8824x; 3.5489x over previous
//
#include <hip/hip_runtime.h>
#include <cfloat>

#define SB 1024   // sequence length S = H*W
#define CC 512    // channels
#define NB 8      // batch
#define NH 8      // heads
#define HD 64     // head dim

typedef short short8 __attribute__((ext_vector_type(8)));
typedef short s16x4 __attribute__((ext_vector_type(4)));
typedef float f32x4 __attribute__((ext_vector_type(4)));

__device__ __forceinline__ short f2bs(float f) {
    union { float f; unsigned u; } x; x.f = f;
    unsigned r = x.u + 0x7fffu + ((x.u >> 16) & 1u);   // RNE to bf16
    return (short)(r >> 16);
}

__device__ __forceinline__ void gload16(const void* g, void* l) {
    __builtin_amdgcn_global_load_lds(
        (const __attribute__((address_space(1))) unsigned int*)g,
        (__attribute__((address_space(3))) unsigned int*)l, 16, 0, 0);
}

// swizzled short-index within a [rows][64-short] LDS tile (128B rows)
__device__ __forceinline__ int sidx(int row, int colb) {
    return row * 64 + ((colb ^ ((row & 7) << 4)) >> 1);
}

// ---------------------------------------------------------------------------
// Convert both weight matrices fp32 -> bf16 (natural [o][c] layout).
// ---------------------------------------------------------------------------
__global__ __launch_bounds__(256)
void cvt_weights(const float* __restrict__ w1, const float* __restrict__ w2,
                 short* __restrict__ o1, short* __restrict__ o2)
{
    const int i4 = blockIdx.x * 256 + threadIdx.x;
    const int N1 = 1536 * 512 / 4;
    if (i4 < N1) {
        float4 v = *(const float4*)&w1[(size_t)i4 * 4];
        s16x4 p; p[0] = f2bs(v.x); p[1] = f2bs(v.y); p[2] = f2bs(v.z); p[3] = f2bs(v.w);
        *(s16x4*)&o1[(size_t)i4 * 4] = p;
    } else {
        const int j = i4 - N1;
        float4 v = *(const float4*)&w2[(size_t)j * 4];
        s16x4 p; p[0] = f2bs(v.x); p[1] = f2bs(v.y); p[2] = f2bs(v.z); p[3] = f2bs(v.w);
        *(s16x4*)&o2[(size_t)j * 4] = p;
    }
}

// ---------------------------------------------------------------------------
// x (B, C, S) fp32  ->  xT (B, S, C) bf16   (64x64 LDS tile transpose)
// ---------------------------------------------------------------------------
__global__ __launch_bounds__(256)
void transpose_x(const float* __restrict__ x, short* __restrict__ xT)
{
    const int bs = blockIdx.x, bc = blockIdx.y, b = blockIdx.z;
    const int tid = threadIdx.x;
    __shared__ short T[64][72];
    {
        const int cl = tid >> 4;
        const int s4 = (tid & 15) * 4;
        #pragma unroll
        for (int r = 0; r < 4; ++r) {
            const int c = cl + 16 * r;
            float4 v = *(const float4*)&x[((size_t)b * CC + bc * 64 + c) * SB + bs * 64 + s4];
            T[s4 + 0][c] = f2bs(v.x); T[s4 + 1][c] = f2bs(v.y);
            T[s4 + 2][c] = f2bs(v.z); T[s4 + 3][c] = f2bs(v.w);
        }
    }
    __syncthreads();
    {
        const int sl = tid >> 2;
        const int c16 = (tid & 3) * 16;
        short8 v0 = *(const short8*)&T[sl][c16];
        short8 v1 = *(const short8*)&T[sl][c16 + 8];
        short* dst = &xT[((size_t)b * SB + bs * 64 + sl) * CC + bc * 64 + c16];
        *(short8*)&dst[0] = v0;
        *(short8*)&dst[8] = v1;
    }
}

// ---------------------------------------------------------------------------
// bf16 MFMA GEMM: Y[b,o,s] = sum_c A[o,c] * X[b,s,c]^T + bias[o]
// 128x128 tile, BK=64, 4 waves (2x2), 4x4 16x16 frags per wave.
// MODE 0 (qkv, M=1536): o<512 -> qT[b,h,s,d] bf16 *0.125 (scale folded);
//                       o<1024 -> kT[b,h,s,d] bf16; else v[b,c,s] bf16.
// MODE 1 (proj, M=512): fp32 out[b,o,s].
// ---------------------------------------------------------------------------
template<int MODE>
__global__ __launch_bounds__(256)
void gemm_bf16(const short* __restrict__ A, const float* __restrict__ bias,
               const short* __restrict__ BT,
               short* __restrict__ qTo, short* __restrict__ kTo,
               short* __restrict__ vo, float* __restrict__ fo)
{
    const int stile = blockIdx.x * 128;
    const int bo    = blockIdx.y;
    const int b     = blockIdx.z;
    const int tid   = threadIdx.x;
    const int wave = tid >> 6, lane = tid & 63, lg = lane >> 4, ln = lane & 15;
    const int wm = wave >> 1, wn = wave & 1;

    __shared__ short Al[128 * 64];
    __shared__ short Bl[128 * 64];

    f32x4 acc[4][4];
    #pragma unroll
    for (int mt = 0; mt < 4; ++mt)
        #pragma unroll
        for (int nt = 0; nt < 4; ++nt) acc[mt][nt] = (f32x4){0.f, 0.f, 0.f, 0.f};

    const char* Ab = (const char*)(A + (size_t)bo * 128 * 512);
    const char* Bb = (const char*)(BT + ((size_t)b * SB + stile) * 512);

    for (int kc = 0; kc < 512; kc += 64) {
        __syncthreads();
        #pragma unroll
        for (int sw = 0; sw < 4; ++sw) {
            const int lin = tid * 16 + sw * 4096;
            const int row = lin >> 7;
            const int scol = (lin & 127) ^ ((row & 7) << 4);
            char* ldst = (char*)nullptr;
            gload16(Ab + ((size_t)row * 512 + kc) * 2 + scol,
                    (char*)Al + (wave << 10) + (sw << 12));
            gload16(Bb + ((size_t)row * 512 + kc) * 2 + scol,
                    (char*)Bl + (wave << 10) + (sw << 12));
            (void)ldst;
        }
        __syncthreads();
        #pragma unroll
        for (int kk = 0; kk < 2; ++kk) {
            const int colb = kk * 64 + lg * 16;
            short8 a[4], bb[4];
            #pragma unroll
            for (int mt = 0; mt < 4; ++mt)
                a[mt] = *(const short8*)&Al[sidx(wm * 64 + mt * 16 + ln, colb)];
            #pragma unroll
            for (int nt = 0; nt < 4; ++nt)
                bb[nt] = *(const short8*)&Bl[sidx(wn * 64 + nt * 16 + ln, colb)];
            #pragma unroll
            for (int mt = 0; mt < 4; ++mt)
                #pragma unroll
                for (int nt = 0; nt < 4; ++nt)
                    acc[mt][nt] = __builtin_amdgcn_mfma_f32_16x16x32_bf16(
                        a[mt], bb[nt], acc[mt][nt], 0, 0, 0);
        }
    }

    const int s_base = stile + wn * 64;
    if (MODE == 0) {
        if (bo < 8) {   // q or k -> transposed [b,h,s,d]
            short* dst = (bo < 4) ? qTo : kTo;
            const int h = (bo & 3) * 2 + wm;
            const float sc = (bo < 4) ? 0.125f : 1.0f;
            #pragma unroll
            for (int mt = 0; mt < 4; ++mt) {
                const int d0 = mt * 16 + 4 * lg;
                const int o0 = bo * 128 + wm * 64 + d0;
                const float b0 = bias[o0], b1 = bias[o0 + 1],
                            b2 = bias[o0 + 2], b3 = bias[o0 + 3];
                #pragma unroll
                for (int nt = 0; nt < 4; ++nt) {
                    const int s = s_base + nt * 16 + ln;
                    s16x4 pk;
                    pk[0] = f2bs((acc[mt][nt][0] + b0) * sc);
                    pk[1] = f2bs((acc[mt][nt][1] + b1) * sc);
                    pk[2] = f2bs((acc[mt][nt][2] + b2) * sc);
                    pk[3] = f2bs((acc[mt][nt][3] + b3) * sc);
                    *(s16x4*)&dst[(((size_t)b * NH + h) * SB + s) * HD + d0] = pk;
                }
            }
        } else {        // v -> natural [b,c,s]
            #pragma unroll
            for (int mt = 0; mt < 4; ++mt) {
                const int cv0 = (bo - 8) * 128 + wm * 64 + mt * 16 + 4 * lg;
                #pragma unroll
                for (int r = 0; r < 4; ++r) {
                    const float bv = bias[1024 + cv0 + r];
                    #pragma unroll
                    for (int nt = 0; nt < 4; ++nt) {
                        const int s = s_base + nt * 16 + ln;
                        vo[((size_t)b * CC + cv0 + r) * SB + s] = f2bs(acc[mt][nt][r] + bv);
                    }
                }
            }
        }
    } else {            // proj -> fp32 out [b,o,s]
        #pragma unroll
        for (int mt = 0; mt < 4; ++mt) {
            #pragma unroll
            for (int r = 0; r < 4; ++r) {
                const int o = bo * 128 + wm * 64 + mt * 16 + 4 * lg + r;
                const float bv = bias[o];
                #pragma unroll
                for (int nt = 0; nt < 4; ++nt) {
                    const int s = s_base + nt * 16 + ln;
                    fo[((size_t)b * CC + o) * SB + s] = acc[mt][nt][r] + bv;
                }
            }
        }
    }
}

// ---------------------------------------------------------------------------
// MFMA bf16 fused attention. Block = (qb, h, b), 4 waves x 16 queries.
// Inputs: qT/kT [b,h,s,d] bf16 (q pre-scaled), v [b,c,s] bf16.
// K/V staged via global_load_lds with XOR swizzle (source+read, linear dest).
// Output: ctxT [b,s,c] bf16, written straight from fragments.
// Processes ALL 16 key tiles so fully-masked rows reproduce the reference's
// uniform softmax exactly via -FLT_MAX arithmetic.
// ---------------------------------------------------------------------------
__global__ __launch_bounds__(256)
void attn_mfma(const short* __restrict__ qT, const short* __restrict__ kT,
               const short* __restrict__ vN, const int* __restrict__ mask,
               short* __restrict__ ctxT)
{
    const int qb  = blockIdx.x;
    const int h   = blockIdx.y;
    const int b   = blockIdx.z;
    const int tid = threadIdx.x;
    const int wave = tid >> 6;
    const int lane = tid & 63;
    const int lg = lane >> 4;
    const int ln = lane & 15;

    __shared__ short Ks[64 * 64];   // [t][d] swizzled
    __shared__ short Vs[64 * 64];   // [d][t] swizzled
    __shared__ short Ps[64][72];    // P [s][t] bf16 (padded, reg-written)
    __shared__ int   msk[64];

    // Q A-fragments from qT (already scaled by 1/8)
    short8 qa0, qa1;
    {
        const short* qrow = qT + (((size_t)b * NH + h) * SB + qb * 64 + wave * 16 + ln) * HD;
        qa0 = *(const short8*)&qrow[8 * lg];
        qa1 = *(const short8*)&qrow[32 + 8 * lg];
    }

    float m_[4], l_[4];
    f32x4 acc[4];
    #pragma unroll
    for (int r = 0; r < 4; ++r) { m_[r] = -FLT_MAX; l_[r] = 0.f; }
    #pragma unroll
    for (int nt = 0; nt < 4; ++nt) acc[nt] = (f32x4){0.f, 0.f, 0.f, 0.f};

    const char* kbh = (const char*)(kT + (((size_t)b * NH + h) * SB) * HD);
    const char* vbh = (const char*)(vN + ((size_t)b * CC + h * HD) * SB);

    for (int t = 0; t < 16; ++t) {
        const int tb = t * 64;
        __syncthreads();   // prev PV reads done before K/V overwrite
        #pragma unroll
        for (int sw = 0; sw < 2; ++sw) {
            const int lin = tid * 16 + sw * 4096;
            const int row = lin >> 7;
            const int scol = (lin & 127) ^ ((row & 7) << 4);
            // K tile: contiguous 8KB at [t=tb..tb+63][d]
            gload16(kbh + (size_t)(tb * 128) + row * 128 + scol,
                    (char*)Ks + (wave << 10) + (sw << 12));
            // V tile: rows d (stride SB*2), cols t
            gload16(vbh + (size_t)row * (SB * 2) + tb * 2 + scol,
                    (char*)Vs + (wave << 10) + (sw << 12));
        }
        if (tid < 64) msk[tid] = mask[(size_t)b * SB + tb + tid];
        __syncthreads();

        // ---- QK^T ----
        f32x4 sc[4];
        #pragma unroll
        for (int nt = 0; nt < 4; ++nt) {
            short8 kb0 = *(const short8*)&Ks[sidx(ln + 16 * nt, lg * 16)];
            short8 kb1 = *(const short8*)&Ks[sidx(ln + 16 * nt, 64 + lg * 16)];
            f32x4 z = (f32x4){0.f, 0.f, 0.f, 0.f};
            z = __builtin_amdgcn_mfma_f32_16x16x32_bf16(qa0, kb0, z, 0, 0, 0);
            z = __builtin_amdgcn_mfma_f32_16x16x32_bf16(qa1, kb1, z, 0, 0, 0);
            sc[nt] = z;
        }

        // ---- mask + online softmax ----
        #pragma unroll
        for (int r = 0; r < 4; ++r) {
            const int sq = qb * 64 + wave * 16 + 4 * lg + r;
            float s4[4];
            float mx = -FLT_MAX;
            #pragma unroll
            for (int nt = 0; nt < 4; ++nt) {
                const int tg = tb + 16 * nt + ln;
                float v = sc[nt][r];
                if (tg > sq || msk[16 * nt + ln] != 0) v = -FLT_MAX;
                s4[nt] = v;
                mx = fmaxf(mx, v);
            }
            #pragma unroll
            for (int o = 1; o < 16; o <<= 1)
                mx = fmaxf(mx, __shfl_xor(mx, o, 64));
            const float mnew = fmaxf(m_[r], mx);
            const float f = __expf(m_[r] - mnew);   // 0-0 -> 1 (all-masked rows)
            float p[4], rs = 0.f;
            #pragma unroll
            for (int nt = 0; nt < 4; ++nt) {
                p[nt] = __expf(s4[nt] - mnew);
                rs += p[nt];
            }
            #pragma unroll
            for (int o = 1; o < 16; o <<= 1)
                rs += __shfl_xor(rs, o, 64);
            l_[r] = l_[r] * f + rs;
            m_[r] = mnew;
            #pragma unroll
            for (int nt = 0; nt < 4; ++nt) acc[nt][r] *= f;
            #pragma unroll
            for (int nt = 0; nt < 4; ++nt)
                Ps[wave * 16 + 4 * lg + r][16 * nt + ln] = f2bs(p[nt]);
        }
        // within-wave Ps dependency only; compiler orders via lgkmcnt

        // ---- PV ----
        short8 pa0 = *(const short8*)&Ps[wave * 16 + ln][8 * lg];
        short8 pa1 = *(const short8*)&Ps[wave * 16 + ln][32 + 8 * lg];
        #pragma unroll
        for (int nt = 0; nt < 4; ++nt) {
            short8 vb0 = *(const short8*)&Vs[sidx(16 * nt + ln, lg * 16)];
            short8 vb1 = *(const short8*)&Vs[sidx(16 * nt + ln, 64 + lg * 16)];
            acc[nt] = __builtin_amdgcn_mfma_f32_16x16x32_bf16(pa0, vb0, acc[nt], 0, 0, 0);
            acc[nt] = __builtin_amdgcn_mfma_f32_16x16x32_bf16(pa1, vb1, acc[nt], 0, 0, 0);
        }
    }

    // ---- epilogue: normalize, store ctxT[b,s,c] bf16 from fragments ----
    float rl[4];
    #pragma unroll
    for (int r = 0; r < 4; ++r) rl[r] = 1.f / l_[r];
    #pragma unroll
    for (int nt = 0; nt < 4; ++nt) {
        const int c = h * HD + 16 * nt + ln;
        #pragma unroll
        for (int r = 0; r < 4; ++r) {
            const int s = qb * 64 + wave * 16 + 4 * lg + r;
            ctxT[((size_t)b * SB + s) * CC + c] = f2bs(acc[nt][r] * rl[r]);
        }
    }
}

extern "C" void kernel_launch(void* const* d_in, const int* in_sizes, int n_in,
                              void* d_out, int out_size, void* d_ws, size_t ws_size,
                              hipStream_t stream) {
    const float* x      = (const float*)d_in[0];
    const int*   amask  = (const int*)d_in[1];
    const float* qkv_w  = (const float*)d_in[2];
    const float* qkv_b  = (const float*)d_in[3];
    const float* proj_w = (const float*)d_in[4];
    const float* proj_b = (const float*)d_in[5];
    float* out = (float*)d_out;

    short* xT   = (short*)d_ws;                       // (B,S,C)
    short* w1b  = xT  + (size_t)NB * SB * CC;         // (1536,512)
    short* w2b  = w1b + (size_t)1536 * 512;           // (512,512)
    short* qT   = w2b + (size_t)512 * 512;            // (B,H,S,D)
    short* kT   = qT  + (size_t)NB * NH * SB * HD;    // (B,H,S,D)
    short* vN   = kT  + (size_t)NB * NH * SB * HD;    // (B,C,S)
    short* ctxT = vN  + (size_t)NB * CC * SB;         // (B,S,C)

    cvt_weights<<<1024, 256, 0, stream>>>(qkv_w, proj_w, w1b, w2b);
    transpose_x<<<dim3(SB / 64, CC / 64, NB), 256, 0, stream>>>(x, xT);
    gemm_bf16<0><<<dim3(8, 12, NB), 256, 0, stream>>>(
        w1b, qkv_b, xT, qT, kT, vN, nullptr);
    attn_mfma<<<dim3(16, NH, NB), 256, 0, stream>>>(qT, kT, vN, amask, ctxT);
    gemm_bf16<1><<<dim3(8, 4, NB), 256, 0, stream>>>(
        w2b, proj_b, ctxT, nullptr, nullptr, nullptr, out);
}

// Round 4
// 114.614 us; speedup vs baseline: 6.2073x; 1.0552x over previous
//
#include <hip/hip_runtime.h>
#include <cfloat>

#define SB 1024   // sequence length S = H*W
#define CC 512    // channels
#define NB 8      // batch
#define NH 8      // heads
#define HD 64     // head dim

typedef short short8 __attribute__((ext_vector_type(8)));
typedef short s16x4 __attribute__((ext_vector_type(4)));
typedef float f32x4 __attribute__((ext_vector_type(4)));

__device__ __forceinline__ short f2bs(float f) {
    union { float f; unsigned u; } x; x.f = f;
    unsigned r = x.u + 0x7fffu + ((x.u >> 16) & 1u);   // RNE to bf16
    return (short)(r >> 16);
}

__device__ __forceinline__ float bs2f(short s) {
    union { unsigned u; float f; } x;
    x.u = ((unsigned)(unsigned short)s) << 16;
    return x.f;
}

__device__ __forceinline__ void gload16(const void* g, void* l) {
    __builtin_amdgcn_global_load_lds(
        (const __attribute__((address_space(1))) unsigned int*)g,
        (__attribute__((address_space(3))) unsigned int*)l, 16, 0, 0);
}

// swizzled short-index within a [rows][64-short] LDS tile (128B rows)
__device__ __forceinline__ int sidx(int row, int colb) {
    return row * 64 + ((colb ^ ((row & 7) << 4)) >> 1);
}

// ---------------------------------------------------------------------------
// Convert both weight matrices fp32 -> bf16 (natural [o][c] layout).
// ---------------------------------------------------------------------------
__global__ __launch_bounds__(256)
void cvt_weights(const float* __restrict__ w1, const float* __restrict__ w2,
                 short* __restrict__ o1, short* __restrict__ o2)
{
    const int i4 = blockIdx.x * 256 + threadIdx.x;
    const int N1 = 1536 * 512 / 4;
    if (i4 < N1) {
        float4 v = *(const float4*)&w1[(size_t)i4 * 4];
        s16x4 p; p[0] = f2bs(v.x); p[1] = f2bs(v.y); p[2] = f2bs(v.z); p[3] = f2bs(v.w);
        *(s16x4*)&o1[(size_t)i4 * 4] = p;
    } else {
        const int j = i4 - N1;
        float4 v = *(const float4*)&w2[(size_t)j * 4];
        s16x4 p; p[0] = f2bs(v.x); p[1] = f2bs(v.y); p[2] = f2bs(v.z); p[3] = f2bs(v.w);
        *(s16x4*)&o2[(size_t)j * 4] = p;
    }
}

// ---------------------------------------------------------------------------
// x (B, C, S) fp32  ->  xT (B, S, C) bf16   (64x64 LDS tile transpose)
// ---------------------------------------------------------------------------
__global__ __launch_bounds__(256)
void transpose_x(const float* __restrict__ x, short* __restrict__ xT)
{
    const int bs = blockIdx.x, bc = blockIdx.y, b = blockIdx.z;
    const int tid = threadIdx.x;
    __shared__ short T[64][72];
    {
        const int cl = tid >> 4;
        const int s4 = (tid & 15) * 4;
        #pragma unroll
        for (int r = 0; r < 4; ++r) {
            const int c = cl + 16 * r;
            float4 v = *(const float4*)&x[((size_t)b * CC + bc * 64 + c) * SB + bs * 64 + s4];
            T[s4 + 0][c] = f2bs(v.x); T[s4 + 1][c] = f2bs(v.y);
            T[s4 + 2][c] = f2bs(v.z); T[s4 + 3][c] = f2bs(v.w);
        }
    }
    __syncthreads();
    {
        const int sl = tid >> 2;
        const int c16 = (tid & 3) * 16;
        short8 v0 = *(const short8*)&T[sl][c16];
        short8 v1 = *(const short8*)&T[sl][c16 + 8];
        short* dst = &xT[((size_t)b * SB + bs * 64 + sl) * CC + bc * 64 + c16];
        *(short8*)&dst[0] = v0;
        *(short8*)&dst[8] = v1;
    }
}

// ---------------------------------------------------------------------------
// vmean[b][c] = (1/S) sum_t v[b][c][t]  -- for uniform-softmax (fully masked)
// rows. One wave per (b,c) row; 16 bf16 per lane.
// ---------------------------------------------------------------------------
__global__ __launch_bounds__(256)
void vmean_kernel(const short* __restrict__ vN, float* __restrict__ vmean)
{
    const int row = blockIdx.x * 4 + (threadIdx.x >> 6);  // b*CC + c
    const int lane = threadIdx.x & 63;
    const short* p = vN + (size_t)row * SB + lane * 16;
    short8 a = *(const short8*)&p[0];
    short8 b8 = *(const short8*)&p[8];
    float s = 0.f;
    #pragma unroll
    for (int j = 0; j < 8; ++j) s += bs2f(a[j]) + bs2f(b8[j]);
    #pragma unroll
    for (int o = 1; o < 64; o <<= 1) s += __shfl_xor(s, o, 64);
    if (lane == 0) vmean[row] = s * (1.f / 1024.f);
}

// ---------------------------------------------------------------------------
// bf16 MFMA GEMM: Y[b,o,s] = sum_c A[o,c] * X[b,s,c]^T + bias[o]
// 128x128 tile, BK=64, 4 waves (2x2), 4x4 16x16 frags per wave.
// MODE 0 (qkv): o<512 -> qT[b,h,s,d] *0.125; o<1024 -> kT[b,h,s,d]; else v[b,c,s].
// MODE 1 (proj): fp32 out[b,o,s].
// ---------------------------------------------------------------------------
template<int MODE>
__global__ __launch_bounds__(256)
void gemm_bf16(const short* __restrict__ A, const float* __restrict__ bias,
               const short* __restrict__ BT,
               short* __restrict__ qTo, short* __restrict__ kTo,
               short* __restrict__ vo, float* __restrict__ fo)
{
    const int stile = blockIdx.x * 128;
    const int bo    = blockIdx.y;
    const int b     = blockIdx.z;
    const int tid   = threadIdx.x;
    const int wave = tid >> 6, lane = tid & 63, lg = lane >> 4, ln = lane & 15;
    const int wm = wave >> 1, wn = wave & 1;

    __shared__ short Al[128 * 64];
    __shared__ short Bl[128 * 64];

    f32x4 acc[4][4];
    #pragma unroll
    for (int mt = 0; mt < 4; ++mt)
        #pragma unroll
        for (int nt = 0; nt < 4; ++nt) acc[mt][nt] = (f32x4){0.f, 0.f, 0.f, 0.f};

    const char* Ab = (const char*)(A + (size_t)bo * 128 * 512);
    const char* Bb = (const char*)(BT + ((size_t)b * SB + stile) * 512);

    for (int kc = 0; kc < 512; kc += 64) {
        __syncthreads();
        #pragma unroll
        for (int sw = 0; sw < 4; ++sw) {
            const int lin = tid * 16 + sw * 4096;
            const int row = lin >> 7;
            const int scol = (lin & 127) ^ ((row & 7) << 4);
            gload16(Ab + ((size_t)row * 512 + kc) * 2 + scol,
                    (char*)Al + (wave << 10) + (sw << 12));
            gload16(Bb + ((size_t)row * 512 + kc) * 2 + scol,
                    (char*)Bl + (wave << 10) + (sw << 12));
        }
        __syncthreads();
        #pragma unroll
        for (int kk = 0; kk < 2; ++kk) {
            const int colb = kk * 64 + lg * 16;
            short8 a[4], bb[4];
            #pragma unroll
            for (int mt = 0; mt < 4; ++mt)
                a[mt] = *(const short8*)&Al[sidx(wm * 64 + mt * 16 + ln, colb)];
            #pragma unroll
            for (int nt = 0; nt < 4; ++nt)
                bb[nt] = *(const short8*)&Bl[sidx(wn * 64 + nt * 16 + ln, colb)];
            #pragma unroll
            for (int mt = 0; mt < 4; ++mt)
                #pragma unroll
                for (int nt = 0; nt < 4; ++nt)
                    acc[mt][nt] = __builtin_amdgcn_mfma_f32_16x16x32_bf16(
                        a[mt], bb[nt], acc[mt][nt], 0, 0, 0);
        }
    }

    const int s_base = stile + wn * 64;
    if (MODE == 0) {
        if (bo < 8) {   // q or k -> transposed [b,h,s,d]
            short* dst = (bo < 4) ? qTo : kTo;
            const int h = (bo & 3) * 2 + wm;
            const float sc = (bo < 4) ? 0.125f : 1.0f;
            #pragma unroll
            for (int mt = 0; mt < 4; ++mt) {
                const int d0 = mt * 16 + 4 * lg;
                const int o0 = bo * 128 + wm * 64 + d0;
                const float b0 = bias[o0], b1 = bias[o0 + 1],
                            b2 = bias[o0 + 2], b3 = bias[o0 + 3];
                #pragma unroll
                for (int nt = 0; nt < 4; ++nt) {
                    const int s = s_base + nt * 16 + ln;
                    s16x4 pk;
                    pk[0] = f2bs((acc[mt][nt][0] + b0) * sc);
                    pk[1] = f2bs((acc[mt][nt][1] + b1) * sc);
                    pk[2] = f2bs((acc[mt][nt][2] + b2) * sc);
                    pk[3] = f2bs((acc[mt][nt][3] + b3) * sc);
                    *(s16x4*)&dst[(((size_t)b * NH + h) * SB + s) * HD + d0] = pk;
                }
            }
        } else {        // v -> natural [b,c,s]
            #pragma unroll
            for (int mt = 0; mt < 4; ++mt) {
                const int cv0 = (bo - 8) * 128 + wm * 64 + mt * 16 + 4 * lg;
                #pragma unroll
                for (int r = 0; r < 4; ++r) {
                    const float bv = bias[1024 + cv0 + r];
                    #pragma unroll
                    for (int nt = 0; nt < 4; ++nt) {
                        const int s = s_base + nt * 16 + ln;
                        vo[((size_t)b * CC + cv0 + r) * SB + s] = f2bs(acc[mt][nt][r] + bv);
                    }
                }
            }
        }
    } else {            // proj -> fp32 out [b,o,s]
        #pragma unroll
        for (int mt = 0; mt < 4; ++mt) {
            #pragma unroll
            for (int r = 0; r < 4; ++r) {
                const int o = bo * 128 + wm * 64 + mt * 16 + 4 * lg + r;
                const float bv = bias[o];
                #pragma unroll
                for (int nt = 0; nt < 4; ++nt) {
                    const int s = s_base + nt * 16 + ln;
                    fo[((size_t)b * CC + o) * SB + s] = acc[mt][nt][r] + bv;
                }
            }
        }
    }
}

// ---------------------------------------------------------------------------
// MFMA bf16 fused attention with causal tile skipping.
// Tiles t in [0, qb] only; rows whose running max stays exactly -FLT_MAX are
// fully masked in the reference (uniform softmax over ALL 1024 keys) and get
// ctx = vmean in the epilogue. Padding mask applied as a float add
// (score + (-FLT_MAX) rounds to exactly -FLT_MAX); causal compare only on the
// diagonal tile (tile-local).
// ---------------------------------------------------------------------------
__global__ __launch_bounds__(256)
void attn_mfma(const short* __restrict__ qT, const short* __restrict__ kT,
               const short* __restrict__ vN, const int* __restrict__ mask,
               const float* __restrict__ vmean, short* __restrict__ ctxT)
{
    const int qb  = blockIdx.x;
    const int h   = blockIdx.y;
    const int b   = blockIdx.z;
    const int tid = threadIdx.x;
    const int wave = tid >> 6;
    const int lane = tid & 63;
    const int lg = lane >> 4;
    const int ln = lane & 15;

    __shared__ short Ks[64 * 64];   // [t][d] swizzled
    __shared__ short Vs[64 * 64];   // [d][t] swizzled
    __shared__ short Ps[64][72];    // P [s][t] bf16 (padded, reg-written)
    __shared__ float mskf[64];      // 0 or -FLT_MAX per key of current tile

    short8 qa0, qa1;
    {
        const short* qrow = qT + (((size_t)b * NH + h) * SB + qb * 64 + wave * 16 + ln) * HD;
        qa0 = *(const short8*)&qrow[8 * lg];
        qa1 = *(const short8*)&qrow[32 + 8 * lg];
    }

    float m_[4], l_[4];
    f32x4 acc[4];
    #pragma unroll
    for (int r = 0; r < 4; ++r) { m_[r] = -FLT_MAX; l_[r] = 0.f; }
    #pragma unroll
    for (int nt = 0; nt < 4; ++nt) acc[nt] = (f32x4){0.f, 0.f, 0.f, 0.f};

    const char* kbh = (const char*)(kT + (((size_t)b * NH + h) * SB) * HD);
    const char* vbh = (const char*)(vN + ((size_t)b * CC + h * HD) * SB);

    for (int t = 0; t <= qb; ++t) {
        const int tb = t * 64;
        __syncthreads();   // prev PV reads done before K/V overwrite
        #pragma unroll
        for (int sw = 0; sw < 2; ++sw) {
            const int lin = tid * 16 + sw * 4096;
            const int row = lin >> 7;
            const int scol = (lin & 127) ^ ((row & 7) << 4);
            gload16(kbh + (size_t)(tb * 128) + row * 128 + scol,
                    (char*)Ks + (wave << 10) + (sw << 12));
            gload16(vbh + (size_t)row * (SB * 2) + tb * 2 + scol,
                    (char*)Vs + (wave << 10) + (sw << 12));
        }
        if (tid < 64)
            mskf[tid] = (mask[(size_t)b * SB + tb + tid] != 0) ? -FLT_MAX : 0.f;
        __syncthreads();

        // ---- QK^T ----
        f32x4 sc[4];
        #pragma unroll
        for (int nt = 0; nt < 4; ++nt) {
            short8 kb0 = *(const short8*)&Ks[sidx(ln + 16 * nt, lg * 16)];
            short8 kb1 = *(const short8*)&Ks[sidx(ln + 16 * nt, 64 + lg * 16)];
            f32x4 z = (f32x4){0.f, 0.f, 0.f, 0.f};
            z = __builtin_amdgcn_mfma_f32_16x16x32_bf16(qa0, kb0, z, 0, 0, 0);
            z = __builtin_amdgcn_mfma_f32_16x16x32_bf16(qa1, kb1, z, 0, 0, 0);
            sc[nt] = z;
        }

        // ---- padding mask (float add) + causal on diagonal tile ----
        {
            float mf[4];
            #pragma unroll
            for (int nt = 0; nt < 4; ++nt) mf[nt] = mskf[16 * nt + ln];
            #pragma unroll
            for (int nt = 0; nt < 4; ++nt)
                #pragma unroll
                for (int r = 0; r < 4; ++r) sc[nt][r] += mf[nt];
        }
        if (t == qb) {
            #pragma unroll
            for (int r = 0; r < 4; ++r) {
                const int so = wave * 16 + 4 * lg + r;   // row within block
                #pragma unroll
                for (int nt = 0; nt < 4; ++nt)
                    if (16 * nt + ln > so) sc[nt][r] = -FLT_MAX;
            }
        }

        // ---- online softmax ----
        #pragma unroll
        for (int r = 0; r < 4; ++r) {
            float mx = fmaxf(fmaxf(sc[0][r], sc[1][r]), fmaxf(sc[2][r], sc[3][r]));
            #pragma unroll
            for (int o = 1; o < 16; o <<= 1)
                mx = fmaxf(mx, __shfl_xor(mx, o, 64));
            const float mnew = fmaxf(m_[r], mx);
            const float f = __expf(m_[r] - mnew);   // 0-0 -> 1 (all-masked rows)
            float p[4], rs = 0.f;
            #pragma unroll
            for (int nt = 0; nt < 4; ++nt) {
                p[nt] = __expf(sc[nt][r] - mnew);
                rs += p[nt];
            }
            #pragma unroll
            for (int o = 1; o < 16; o <<= 1)
                rs += __shfl_xor(rs, o, 64);
            l_[r] = l_[r] * f + rs;
            m_[r] = mnew;
            #pragma unroll
            for (int nt = 0; nt < 4; ++nt) acc[nt][r] *= f;
            #pragma unroll
            for (int nt = 0; nt < 4; ++nt)
                Ps[wave * 16 + 4 * lg + r][16 * nt + ln] = f2bs(p[nt]);
        }
        // within-wave Ps dependency only; compiler orders via lgkmcnt

        // ---- PV ----
        short8 pa0 = *(const short8*)&Ps[wave * 16 + ln][8 * lg];
        short8 pa1 = *(const short8*)&Ps[wave * 16 + ln][32 + 8 * lg];
        #pragma unroll
        for (int nt = 0; nt < 4; ++nt) {
            short8 vb0 = *(const short8*)&Vs[sidx(16 * nt + ln, lg * 16)];
            short8 vb1 = *(const short8*)&Vs[sidx(16 * nt + ln, 64 + lg * 16)];
            acc[nt] = __builtin_amdgcn_mfma_f32_16x16x32_bf16(pa0, vb0, acc[nt], 0, 0, 0);
            acc[nt] = __builtin_amdgcn_mfma_f32_16x16x32_bf16(pa1, vb1, acc[nt], 0, 0, 0);
        }
    }

    // ---- epilogue: normalize (or vmean for fully-masked rows), store ----
    float rl[4];
    #pragma unroll
    for (int r = 0; r < 4; ++r) rl[r] = 1.f / l_[r];
    const float* vmb = vmean + (size_t)b * CC + h * HD;
    #pragma unroll
    for (int nt = 0; nt < 4; ++nt) {
        const int c = h * HD + 16 * nt + ln;
        const float vmv = vmb[16 * nt + ln];
        #pragma unroll
        for (int r = 0; r < 4; ++r) {
            const int s = qb * 64 + wave * 16 + 4 * lg + r;
            const float val = (m_[r] == -FLT_MAX) ? vmv : acc[nt][r] * rl[r];
            ctxT[((size_t)b * SB + s) * CC + c] = f2bs(val);
        }
    }
}

extern "C" void kernel_launch(void* const* d_in, const int* in_sizes, int n_in,
                              void* d_out, int out_size, void* d_ws, size_t ws_size,
                              hipStream_t stream) {
    const float* x      = (const float*)d_in[0];
    const int*   amask  = (const int*)d_in[1];
    const float* qkv_w  = (const float*)d_in[2];
    const float* qkv_b  = (const float*)d_in[3];
    const float* proj_w = (const float*)d_in[4];
    const float* proj_b = (const float*)d_in[5];
    float* out = (float*)d_out;

    short* xT    = (short*)d_ws;                       // (B,S,C)
    short* w1b   = xT  + (size_t)NB * SB * CC;         // (1536,512)
    short* w2b   = w1b + (size_t)1536 * 512;           // (512,512)
    short* qT    = w2b + (size_t)512 * 512;            // (B,H,S,D)
    short* kT    = qT  + (size_t)NB * NH * SB * HD;    // (B,H,S,D)
    short* vN    = kT  + (size_t)NB * NH * SB * HD;    // (B,C,S)
    short* ctxT  = vN  + (size_t)NB * CC * SB;         // (B,S,C)
    float* vmean = (float*)(ctxT + (size_t)NB * SB * CC);  // (B,C)

    cvt_weights<<<1024, 256, 0, stream>>>(qkv_w, proj_w, w1b, w2b);
    transpose_x<<<dim3(SB / 64, CC / 64, NB), 256, 0, stream>>>(x, xT);
    gemm_bf16<0><<<dim3(8, 12, NB), 256, 0, stream>>>(
        w1b, qkv_b, xT, qT, kT, vN, nullptr);
    vmean_kernel<<<NB * CC / 4, 256, 0, stream>>>(vN, vmean);
    attn_mfma<<<dim3(16, NH, NB), 256, 0, stream>>>(qT, kT, vN, amask, vmean, ctxT);
    gemm_bf16<1><<<dim3(8, 4, NB), 256, 0, stream>>>(
        w2b, proj_b, ctxT, nullptr, nullptr, nullptr, out);
}